// Round 14
// baseline (99.054 us; speedup 1.0000x reference)
//
#include <hip/hip_runtime.h>
#include <hip/hip_bf16.h>

// CosSim2D (K=3, same-pad, C=32 -> F=32) on MI355X.
// Round 14: r13 retried WITHOUT the register spill that confounded it.
//   r13's 95us: (256,4) 128-VGPR cap spilled bfrag[18] (72 regs) to scratch
//   (WRITE 50->225MB, FETCH 33->138MB = the regression). Fix: each compute
//   half needs only 9 fragments -> hold 36 VGPRs, load half1's set during
//   half1's DMA issue (bfragA dead by then). Peak ~105 VGPR < 128 -> real
//   4 blk/CU (16 waves, +33% TLP vs r12) with a 24.6KB single-half buffer.
//   Keeps: DMA staging, XCD swizzle, fused psum, NT stores, fast path.

#define H_ 224
#define W_ 224
#define C_ 32
#define F_ 32

#define HROWS 10   // staged halo rows (8 + 2)
#define HCOLS 34   // staged halo cols (32 + 2)
#define NPIX (HROWS * HCOLS)   // 340 pixels
#define HGRAN (NPIX * 4)       // 1360 16B granules per chunk-half
#define HPAD 1536              // 6 * 256 slots (pad slots -> zpool)
#define NSTEP 18

typedef __bf16 bf16_t;
typedef bf16_t bf16x8 __attribute__((ext_vector_type(8)));
typedef float f32x16 __attribute__((ext_vector_type(16)));

#define WFRAG_BYTES (NSTEP * 64 * 8 * 2)  // 18432 B

__device__ __forceinline__ void dma16(const void* gp, void* lp) {
  __builtin_amdgcn_global_load_lds(
      (const __attribute__((address_space(1))) void*)gp,
      (__attribute__((address_space(3))) void*)lp, 16, 0, 0);
}

// ---------------- prep (6 blocks): w-norm, exponents, B-frags, zero pool ----
__global__ __launch_bounds__(256) void cos2d_prep(
    const float* __restrict__ w, const float* __restrict__ p,
    const float* __restrict__ q, bf16_t* __restrict__ wfrag,
    float* __restrict__ winv, float* __restrict__ ef,
    float* __restrict__ zpool) {
  const int tid = threadIdx.x;
  if (blockIdx.x == 0) {
    __shared__ float part[8][32];
    const int f = tid & 31, kg = tid >> 5;
    float s = 0.f;
#pragma unroll
    for (int i = 0; i < 36; ++i) {
      const float v = w[(kg + 8 * i) * F_ + f];
      s += v * v;
    }
    part[kg][f] = s;
    zpool[tid] = 0.f;     // 1KB zero pool for OOB/pad DMA sources
    __syncthreads();
    if (tid < 32) {
      float t = 0.f;
#pragma unroll
      for (int g = 0; g < 8; ++g) t += part[g][tid];
      const float qt = q[0] * q[0] * 0.1f;
      winv[tid] = 1.f / (sqrtf(fmaxf(t, 1e-12f)) + qt);
      ef[tid] = p[tid] * p[tid] * 0.01f;
    }
  } else {
    // B-fragment layout for mfma_f32_32x32x16_bf16:
    //   lane l holds col f = l&31, k = s2*16 + (l>>5)*8 + e  (e = 0..7).
    const int t = (blockIdx.x - 1) * 256 + tid;
    if (t < NSTEP * 64) {
      const int s2 = t >> 6, l = t & 63;
      const int ff = l & 31;
      union { bf16_t v[8]; uint4 u; } tv;
#pragma unroll
      for (int e = 0; e < 8; ++e) {
        const int kk = s2 * 16 + ((l >> 5) << 3) + e;
        tv.v[e] = (bf16_t)w[kk * F_ + ff];
      }
      *(uint4*)(wfrag + (size_t)t * 8) = tv.u;
    }
  }
}

// ---------------- main ------------------------------------------------------
__global__ __launch_bounds__(256, 4) void cos2d_main(
    const float* __restrict__ img, const bf16_t* __restrict__ wfrag,
    const float* __restrict__ winv, const float* __restrict__ ef,
    const float* __restrict__ q, const float* __restrict__ zpool,
    float* __restrict__ out) {
  // ONE chunk-half region (reused for both halves). Pixel p's chunk c lives
  // at granule p*4 + ((c&3) ^ ((p>>1)&3)) -> 8 consecutive pixels at fixed c
  // cover all 8 bank-groups (conflict-free b128 reads; as r10/r12).
  __shared__ __align__(16) float xt[HPAD * 4];  // 24576 B -> 4 blk/CU

  const int tid = threadIdx.x;
  const int lane = tid & 63;
  const int wv = tid >> 6;
  const int lp = lane & 31;
  const int hi2 = (lane >> 5) * 2;   // chunk offset within half per lane-half

  // XCD-bijective mapping: image b == XCD (bid&7); tl walks tiles per image.
  const int bid = blockIdx.x;
  const int b  = bid & 7;
  const int tl = bid >> 3;           // 0..195
  const int tw = tl % 7, th = tl / 7;
  const int h0 = th * 8, w0 = tw * 32;

  const float qt = q[0] * q[0] * 0.1f;
  const float efv = ef[lp];
  const float wnv = winv[lp];
  const bool allfast = __all(__builtin_fabsf(efv - 1.0f) < 1e-6f);

  const bf16x8* wf4 = (const bf16x8*)wfrag;

  // ---- stage one chunk-half: EXACTLY 6 DMA per thread (pad/OOB -> zpool)
  auto stage_half = [&](int half) {
#pragma unroll
    for (int k = 0; k < 6; ++k) {
      const int u = k * 256 + tid;
      float* lb = &xt[(size_t)(k * 256 + wv * 64) * 4];  // wave-uniform base
      const int uc = u < HGRAN ? u : 0;
      const int pp = uc >> 2;
      const int c  = half * 4 + ((uc & 3) ^ ((pp >> 1) & 3));
      const int rr = pp / HCOLS, cc = pp - rr * HCOLS;
      const int hh = h0 - 1 + rr, wc = w0 - 1 + cc;
      const bool live = (u < HGRAN) & ((unsigned)hh < H_) & ((unsigned)wc < W_);
      const float* src = live
          ? img + ((size_t)(b * H_ + hh) * W_ + wc) * C_ + c * 4
          : zpool + lane * 4;
      dma16(src, lb);
    }
  };

  const int mr0 = wv * 2;  // this wave's 2 output rows (tile-relative)

  f32x16 acc0, acc1;
#pragma unroll
  for (int i = 0; i < 16; ++i) { acc0[i] = 0.f; acc1[i] = 0.f; }
  float psum[4] = {0.f, 0.f, 0.f, 0.f};

  // ---- compute one channel-half; frags = this half's 9 B-fragments
  auto compute_half = [&](const bf16x8* frags) {
#pragma unroll
    for (int dx = 0; dx < 3; ++dx) {
      bf16x8 af[4];
#pragma unroll
      for (int r = 0; r < 4; ++r) {
        const int p = (mr0 + r) * HCOLS + lp + dx;
        const int pj = (p >> 1) & 3;
        const int g0 = p * 4 + (hi2 ^ pj);
        const int g1 = p * 4 + ((hi2 + 1) ^ pj);
        const float4 f0 = *(const float4*)&xt[(size_t)g0 * 4];
        const float4 f1 = *(const float4*)&xt[(size_t)g1 * 4];
        psum[r] += f0.x * f0.x + f0.y * f0.y + f0.z * f0.z + f0.w * f0.w +
                   f1.x * f1.x + f1.y * f1.y + f1.z * f1.z + f1.w * f1.w;
        bf16x8 a;
        a[0] = (bf16_t)f0.x; a[1] = (bf16_t)f0.y;
        a[2] = (bf16_t)f0.z; a[3] = (bf16_t)f0.w;
        a[4] = (bf16_t)f1.x; a[5] = (bf16_t)f1.y;
        a[6] = (bf16_t)f1.z; a[7] = (bf16_t)f1.w;
        af[r] = a;
      }
#pragma unroll
      for (int dy = 0; dy < 3; ++dy) {
        const bf16x8 bf = frags[dy * 3 + dx];
        acc0 = __builtin_amdgcn_mfma_f32_32x32x16_bf16(af[dy],     bf, acc0, 0, 0, 0);
        acc1 = __builtin_amdgcn_mfma_f32_32x32x16_bf16(af[dy + 1], bf, acc1, 0, 0, 0);
      }
    }
  };

  // ---- 4-phase schedule on one half-buffer, per-half 9-frag B preload
  {
    stage_half(0);
    bf16x8 bfragA[9];
#pragma unroll
    for (int pos = 0; pos < 9; ++pos)       // half-0 set: bfrag[2*pos+0]
      bfragA[pos] = wf4[(2 * pos + 0) * 64 + lane];
    __syncthreads();     // vmcnt(0)+barrier: half0 + bfragA resident
    compute_half(bfragA);
  }
  __syncthreads();       // all waves done reading half0
  {
    bf16x8 bfragB[9];
#pragma unroll
    for (int pos = 0; pos < 9; ++pos)       // half-1 set: bfrag[2*pos+1]
      bfragB[pos] = wf4[(2 * pos + 1) * 64 + lane];
    stage_half(1);
    __syncthreads();     // half1 + bfragB resident
    compute_half(bfragB);
  }

  // x-norm from fused sums: lane and lane^32 hold complementary 16 channels.
#pragma unroll
  for (int r = 0; r < 4; ++r) psum[r] += __shfl_xor(psum[r], 32);
  float xinv[2];
  xinv[0] = 1.f / (sqrtf(fmaxf(psum[0] + psum[1] + psum[2], 1e-12f)) + qt);
  xinv[1] = 1.f / (sqrtf(fmaxf(psum[1] + psum[2] + psum[3], 1e-12f)) + qt);

  // epilogue: C/D col = lane&31 (filter), row = (j&3)+8*(j>>2)+4*(lane>>5).
#pragma unroll
  for (int t = 0; t < 2; ++t) {
    const f32x16& acc = t ? acc1 : acc0;
    const int obase = (b * H_ + h0 + mr0 + t) * W_ + w0;
    if (allfast) {
#pragma unroll
      for (int jj = 0; jj < 16; ++jj) {
        const int row = (jj & 3) + 8 * (jj >> 2) + 4 * (lane >> 5);
        const float xi = __shfl(xinv[t], row);
        const float sim = acc[jj] * xi * wnv;
        const float r = copysignf(fabsf(sim) + 1e-12f, sim);  // |x|^1 path
        __builtin_nontemporal_store(r, &out[(size_t)(obase + row) * F_ + lp]);
      }
    } else {
#pragma unroll
      for (int jj = 0; jj < 16; ++jj) {
        const int row = (jj & 3) + 8 * (jj >> 2) + 4 * (lane >> 5);
        const float xi = __shfl(xinv[t], row);
        const float sim = acc[jj] * xi * wnv;
        const float ps = fabsf(sim) + 1e-12f;
        float r = exp2f(efv * __log2f(ps));
        r = copysignf(r, sim);
        __builtin_nontemporal_store(r, &out[(size_t)(obase + row) * F_ + lp]);
      }
    }
  }
}

// ---------------- launch ----------------------------------------------------
extern "C" void kernel_launch(void* const* d_in, const int* in_sizes, int n_in,
                              void* d_out, int out_size, void* d_ws, size_t ws_size,
                              hipStream_t stream) {
  const float* img = (const float*)d_in[0];
  const float* w   = (const float*)d_in[1];
  const float* p   = (const float*)d_in[2];
  const float* q   = (const float*)d_in[3];

  bf16_t* wfrag = (bf16_t*)d_ws;
  float*  winv  = (float*)((char*)d_ws + WFRAG_BYTES);
  float*  ef    = winv + 64;
  float*  zpool = ef + 64;   // 256 floats = 1KB zeros

  cos2d_prep<<<6, 256, 0, stream>>>(w, p, q, wfrag, winv, ef, zpool);
  // 1568 blocks: image = bid&7 (== XCD), tile-in-image = bid>>3.
  cos2d_main<<<1568, 256, 0, stream>>>(img, wfrag, winv, ef, q, zpool,
                                       (float*)d_out);
}

// Round 16
// 84.852 us; speedup vs baseline: 1.1674x; 1.1674x over previous
//
#include <hip/hip_runtime.h>
#include <hip/hip_bf16.h>

// CosSim2D (K=3, same-pad, C=32 -> F=32) on MI355X.
// Round 16: r15 with the LDS overflow FIXED.
//   r15's absmax 4e-2: xt was shrunk to 1488 granules but stage_half writes
//   pad granules up to 1535 -> last 48 granules overflowed into wlds,
//   corrupting B fragments. Restore xt to the full padded 1536 granules
//   (24576B). Total LDS 33792B -> still 4 blk/CU (16 waves): this finally
//   runs the TLP experiment spill-free (B frags in LDS, not VGPRs).

#define H_ 224
#define W_ 224
#define C_ 32
#define F_ 32

#define HROWS 10   // staged halo rows (8 + 2)
#define HCOLS 34   // staged halo cols (32 + 2)
#define NPIX (HROWS * HCOLS)   // 340 pixels
#define HGRAN (NPIX * 4)       // 1360 16B granules per image chunk-half
#define HPAD 1536              // 6*256: full padded slot count (pad->zpool)
#define NSTEP 18
#define BGRAN 576              // 9 steps * 64 lanes, 16B each (one B half)

typedef __bf16 bf16_t;
typedef bf16_t bf16x8 __attribute__((ext_vector_type(8)));
typedef float f32x16 __attribute__((ext_vector_type(16)));

#define WFRAG_BYTES (NSTEP * 64 * 8 * 2)  // 18432 B

__device__ __forceinline__ void dma16(const void* gp, void* lp) {
  __builtin_amdgcn_global_load_lds(
      (const __attribute__((address_space(1))) void*)gp,
      (__attribute__((address_space(3))) void*)lp, 16, 0, 0);
}

// ---------------- prep (6 blocks): w-norm, exponents, B-frags, zero pool ----
__global__ __launch_bounds__(256) void cos2d_prep(
    const float* __restrict__ w, const float* __restrict__ p,
    const float* __restrict__ q, bf16_t* __restrict__ wfrag,
    float* __restrict__ winv, float* __restrict__ ef,
    float* __restrict__ zpool) {
  const int tid = threadIdx.x;
  if (blockIdx.x == 0) {
    __shared__ float part[8][32];
    const int f = tid & 31, kg = tid >> 5;
    float s = 0.f;
#pragma unroll
    for (int i = 0; i < 36; ++i) {
      const float v = w[(kg + 8 * i) * F_ + f];
      s += v * v;
    }
    part[kg][f] = s;
    zpool[tid] = 0.f;     // 1KB zero pool for OOB/pad DMA sources
    __syncthreads();
    if (tid < 32) {
      float t = 0.f;
#pragma unroll
      for (int g = 0; g < 8; ++g) t += part[g][tid];
      const float qt = q[0] * q[0] * 0.1f;
      winv[tid] = 1.f / (sqrtf(fmaxf(t, 1e-12f)) + qt);
      ef[tid] = p[tid] * p[tid] * 0.01f;
    }
  } else {
    // B-fragment layout for mfma_f32_32x32x16_bf16:
    //   lane l holds col f = l&31, k = s2*16 + (l>>5)*8 + e  (e = 0..7).
    const int t = (blockIdx.x - 1) * 256 + tid;
    if (t < NSTEP * 64) {
      const int s2 = t >> 6, l = t & 63;
      const int ff = l & 31;
      union { bf16_t v[8]; uint4 u; } tv;
#pragma unroll
      for (int e = 0; e < 8; ++e) {
        const int kk = s2 * 16 + ((l >> 5) << 3) + e;
        tv.v[e] = (bf16_t)w[kk * F_ + ff];
      }
      *(uint4*)(wfrag + (size_t)t * 8) = tv.u;
    }
  }
}

// ---------------- main ------------------------------------------------------
__global__ __launch_bounds__(256, 4) void cos2d_main(
    const float* __restrict__ img, const bf16_t* __restrict__ wfrag,
    const float* __restrict__ winv, const float* __restrict__ ef,
    const float* __restrict__ q, const float* __restrict__ zpool,
    float* __restrict__ out) {
  // Image chunk-half (FULL padded 1536 granules — pad writes must stay
  // inside xt): pixel p chunk c at granule p*4 + ((c&3)^((p>>1)&3)) ->
  // conflict-free b128 reads. B half: [9][64][8] bf16, lane-linear reads.
  __shared__ __align__(16) float xt[HPAD * 4];     // 24576 B
  __shared__ __align__(16) bf16_t wlds[9][64][8];  //  9216 B  (33792 total)

  const int tid = threadIdx.x;
  const int lane = tid & 63;
  const int wv = tid >> 6;
  const int lp = lane & 31;
  const int hi2 = (lane >> 5) * 2;   // chunk offset within half per lane-half

  // XCD-bijective mapping: image b == XCD (bid&7); tl walks tiles per image.
  const int bid = blockIdx.x;
  const int b  = bid & 7;
  const int tl = bid >> 3;           // 0..195
  const int tw = tl % 7, th = tl / 7;
  const int h0 = th * 8, w0 = tw * 32;

  const float qt = q[0] * q[0] * 0.1f;
  const float efv = ef[lp];
  const float wnv = winv[lp];
  const bool allfast = __all(__builtin_fabsf(efv - 1.0f) < 1e-6f);

  // ---- stage one half: 6 image DMAs (pad/OOB -> zpool) + 9/64 B-half DMAs
  auto stage_half = [&](int half) {
#pragma unroll
    for (int k = 0; k < 6; ++k) {
      const int u = k * 256 + tid;
      float* lb = &xt[(size_t)(k * 256 + wv * 64) * 4];  // wave-uniform base
      const int uc = u < HGRAN ? u : 0;
      const int pp = uc >> 2;
      const int c  = half * 4 + ((uc & 3) ^ ((pp >> 1) & 3));
      const int rr = pp / HCOLS, cc = pp - rr * HCOLS;
      const int hh = h0 - 1 + rr, wc = w0 - 1 + cc;
      const bool live = (u < HGRAN) & ((unsigned)hh < H_) & ((unsigned)wc < W_);
      const float* src = live
          ? img + ((size_t)(b * H_ + hh) * W_ + wc) * C_ + c * 4
          : zpool + lane * 4;
      dma16(src, lb);
    }
    // B-half: 576 granules; slot s -> pos=s>>6, l=s&63;
    // src = wfrag granule (2*pos+half)*64 + l. 576 = 9*64 -> wave-uniform cut.
#pragma unroll
    for (int k = 0; k < 3; ++k) {
      const int s0 = k * 256 + wv * 64;
      if (s0 < BGRAN) {
        const int s = k * 256 + tid;
        const int pos = s >> 6, l = s & 63;
        bf16_t* lb = &wlds[0][0][0] + (size_t)s0 * 8;    // wave-uniform base
        dma16(wfrag + ((size_t)(2 * pos + half) * 64 + l) * 8, lb);
      }
    }
  };

  const int mr0 = wv * 2;  // this wave's 2 output rows (tile-relative)

  f32x16 acc0, acc1;
#pragma unroll
  for (int i = 0; i < 16; ++i) { acc0[i] = 0.f; acc1[i] = 0.f; }
  float psum[4] = {0.f, 0.f, 0.f, 0.f};

  // ---- compute one channel-half; B fragments read from wlds
  auto compute_half = [&]() {
#pragma unroll
    for (int dx = 0; dx < 3; ++dx) {
      bf16x8 af[4];
#pragma unroll
      for (int r = 0; r < 4; ++r) {
        const int p = (mr0 + r) * HCOLS + lp + dx;
        const int pj = (p >> 1) & 3;
        const int g0 = p * 4 + (hi2 ^ pj);
        const int g1 = p * 4 + ((hi2 + 1) ^ pj);
        const float4 f0 = *(const float4*)&xt[(size_t)g0 * 4];
        const float4 f1 = *(const float4*)&xt[(size_t)g1 * 4];
        psum[r] += f0.x * f0.x + f0.y * f0.y + f0.z * f0.z + f0.w * f0.w +
                   f1.x * f1.x + f1.y * f1.y + f1.z * f1.z + f1.w * f1.w;
        bf16x8 a;
        a[0] = (bf16_t)f0.x; a[1] = (bf16_t)f0.y;
        a[2] = (bf16_t)f0.z; a[3] = (bf16_t)f0.w;
        a[4] = (bf16_t)f1.x; a[5] = (bf16_t)f1.y;
        a[6] = (bf16_t)f1.z; a[7] = (bf16_t)f1.w;
        af[r] = a;
      }
#pragma unroll
      for (int dy = 0; dy < 3; ++dy) {
        const bf16x8 bf = *(const bf16x8*)&wlds[dy * 3 + dx][lane][0];
        acc0 = __builtin_amdgcn_mfma_f32_32x32x16_bf16(af[dy],     bf, acc0, 0, 0, 0);
        acc1 = __builtin_amdgcn_mfma_f32_32x32x16_bf16(af[dy + 1], bf, acc1, 0, 0, 0);
      }
    }
  };

  // ---- 4-phase schedule on the shared half-buffers
  stage_half(0);
  __syncthreads();     // vmcnt(0)+barrier: image-half0 + B-half0 resident
  compute_half();
  __syncthreads();     // all waves done reading half0
  stage_half(1);
  __syncthreads();     // half1 resident
  compute_half();

  // x-norm from fused sums: lane and lane^32 hold complementary 16 channels.
#pragma unroll
  for (int r = 0; r < 4; ++r) psum[r] += __shfl_xor(psum[r], 32);
  float xinv[2];
  xinv[0] = 1.f / (sqrtf(fmaxf(psum[0] + psum[1] + psum[2], 1e-12f)) + qt);
  xinv[1] = 1.f / (sqrtf(fmaxf(psum[1] + psum[2] + psum[3], 1e-12f)) + qt);

  // epilogue: C/D col = lane&31 (filter), row = (j&3)+8*(j>>2)+4*(lane>>5).
#pragma unroll
  for (int t = 0; t < 2; ++t) {
    const f32x16& acc = t ? acc1 : acc0;
    const int obase = (b * H_ + h0 + mr0 + t) * W_ + w0;
    if (allfast) {
#pragma unroll
      for (int jj = 0; jj < 16; ++jj) {
        const int row = (jj & 3) + 8 * (jj >> 2) + 4 * (lane >> 5);
        const float xi = __shfl(xinv[t], row);
        const float sim = acc[jj] * xi * wnv;
        const float r = copysignf(fabsf(sim) + 1e-12f, sim);  // |x|^1 path
        __builtin_nontemporal_store(r, &out[(size_t)(obase + row) * F_ + lp]);
      }
    } else {
#pragma unroll
      for (int jj = 0; jj < 16; ++jj) {
        const int row = (jj & 3) + 8 * (jj >> 2) + 4 * (lane >> 5);
        const float xi = __shfl(xinv[t], row);
        const float sim = acc[jj] * xi * wnv;
        const float ps = fabsf(sim) + 1e-12f;
        float r = exp2f(efv * __log2f(ps));
        r = copysignf(r, sim);
        __builtin_nontemporal_store(r, &out[(size_t)(obase + row) * F_ + lp]);
      }
    }
  }
}

// ---------------- launch ----------------------------------------------------
extern "C" void kernel_launch(void* const* d_in, const int* in_sizes, int n_in,
                              void* d_out, int out_size, void* d_ws, size_t ws_size,
                              hipStream_t stream) {
  const float* img = (const float*)d_in[0];
  const float* w   = (const float*)d_in[1];
  const float* p   = (const float*)d_in[2];
  const float* q   = (const float*)d_in[3];

  bf16_t* wfrag = (bf16_t*)d_ws;
  float*  winv  = (float*)((char*)d_ws + WFRAG_BYTES);
  float*  ef    = winv + 64;
  float*  zpool = ef + 64;   // 256 floats = 1KB zeros

  cos2d_prep<<<6, 256, 0, stream>>>(w, p, q, wfrag, winv, ef, zpool);
  // 1568 blocks: image = bid&7 (== XCD), tile-in-image = bid>>3.
  cos2d_main<<<1568, 256, 0, stream>>>(img, wfrag, winv, ef, q, zpool,
                                       (float*)d_out);
}

// Round 17
// 77.861 us; speedup vs baseline: 1.2722x; 1.0898x over previous
//
#include <hip/hip_runtime.h>
#include <hip/hip_bf16.h>

// CosSim2D (K=3, same-pad, C=32 -> F=32) on MI355X.
// Round 17: r12 (best, 31.4us) + cross-tile counted-vmcnt pipeline.
//   TLP chase closed (r3: 20 waves = 36us vs r12: 12 waves = 31.4us; and
//   (256,4) always spills this code shape). Extend r12's proven split-wait:
//   2 tiles per block (grid 784). While computing t0.h1 + epilogue, t1.h0's
//   6 DMAs fly (vmcnt(32) = 6 DMA + 32 NT stores, issue-order pinned by
//   sched_barrier). While computing t1.h0, t1.h1 flies. Same LDS (48KB),
//   same VGPR budget (256,3) -> 3 blk/CU, no spill.

#define H_ 224
#define W_ 224
#define C_ 32
#define F_ 32

#define HROWS 10   // staged halo rows (8 + 2)
#define HCOLS 34   // staged halo cols (32 + 2)
#define NPIX (HROWS * HCOLS)   // 340 pixels
#define HGRAN (NPIX * 4)       // 1360 16B granules per chunk-half
#define HPAD 1536              // 6 * 256 slots (pad slots -> zpool)
#define NSTEP 18

typedef __bf16 bf16_t;
typedef bf16_t bf16x8 __attribute__((ext_vector_type(8)));
typedef float f32x16 __attribute__((ext_vector_type(16)));

#define WFRAG_BYTES (NSTEP * 64 * 8 * 2)  // 18432 B

__device__ __forceinline__ void dma16(const void* gp, void* lp) {
  __builtin_amdgcn_global_load_lds(
      (const __attribute__((address_space(1))) void*)gp,
      (__attribute__((address_space(3))) void*)lp, 16, 0, 0);
}

// ---------------- prep (6 blocks): w-norm, exponents, B-frags, zero pool ----
__global__ __launch_bounds__(256) void cos2d_prep(
    const float* __restrict__ w, const float* __restrict__ p,
    const float* __restrict__ q, bf16_t* __restrict__ wfrag,
    float* __restrict__ winv, float* __restrict__ ef,
    float* __restrict__ zpool) {
  const int tid = threadIdx.x;
  if (blockIdx.x == 0) {
    __shared__ float part[8][32];
    const int f = tid & 31, kg = tid >> 5;
    float s = 0.f;
#pragma unroll
    for (int i = 0; i < 36; ++i) {
      const float v = w[(kg + 8 * i) * F_ + f];
      s += v * v;
    }
    part[kg][f] = s;
    zpool[tid] = 0.f;     // 1KB zero pool for OOB/pad DMA sources
    __syncthreads();
    if (tid < 32) {
      float t = 0.f;
#pragma unroll
      for (int g = 0; g < 8; ++g) t += part[g][tid];
      const float qt = q[0] * q[0] * 0.1f;
      winv[tid] = 1.f / (sqrtf(fmaxf(t, 1e-12f)) + qt);
      ef[tid] = p[tid] * p[tid] * 0.01f;
    }
  } else {
    // B-fragment layout for mfma_f32_32x32x16_bf16:
    //   lane l holds col f = l&31, k = s2*16 + (l>>5)*8 + e  (e = 0..7).
    const int t = (blockIdx.x - 1) * 256 + tid;
    if (t < NSTEP * 64) {
      const int s2 = t >> 6, l = t & 63;
      const int ff = l & 31;
      union { bf16_t v[8]; uint4 u; } tv;
#pragma unroll
      for (int e = 0; e < 8; ++e) {
        const int kk = s2 * 16 + ((l >> 5) << 3) + e;
        tv.v[e] = (bf16_t)w[kk * F_ + ff];
      }
      *(uint4*)(wfrag + (size_t)t * 8) = tv.u;
    }
  }
}

// ---------------- main ------------------------------------------------------
__global__ __launch_bounds__(256, 3) void cos2d_main(
    const float* __restrict__ img, const bf16_t* __restrict__ wfrag,
    const float* __restrict__ winv, const float* __restrict__ ef,
    const float* __restrict__ q, const float* __restrict__ zpool,
    float* __restrict__ out) {
  // Two chunk-half buffers (A = half0, B = half1), r12 layout: within a
  // half, pixel p's chunk c at granule p*4 + ((c&3) ^ ((p>>1)&3)).
  __shared__ __align__(16) float xt[2 * HPAD * 4];  // 49152 B -> 3 blk/CU

  const int tid = threadIdx.x;
  const int lane = tid & 63;
  const int wv = tid >> 6;
  const int lp = lane & 31;
  const int hi2 = (lane >> 5) * 2;

  // 2 tiles per block: t0 = bid, t1 = bid + 784 (same image: 784 % 8 == 0).
  const int bid = blockIdx.x;
  const int b   = bid & 7;            // image == XCD
  const int tl0 = bid >> 3;           // 0..97
  const int th0 = tl0 / 7, tw0 = tl0 % 7;
  const int tl1 = tl0 + 98;           // 98..195
  const int th1 = tl1 / 7, tw1 = tl1 % 7;

  const float qt = q[0] * q[0] * 0.1f;
  const float efv = ef[lp];
  const float wnv = winv[lp];
  const bool allfast = __all(__builtin_fabsf(efv - 1.0f) < 1e-6f);

  // ---- preload all 18 B-fragments (issued first; drained by vmcnt(6))
  bf16x8 bfrag[NSTEP];
  const bf16x8* wf4 = (const bf16x8*)wfrag;
#pragma unroll
  for (int s2 = 0; s2 < NSTEP; ++s2) bfrag[s2] = wf4[s2 * 64 + lane];

  // ---- stage one chunk-half of a tile: EXACTLY 6 DMA per thread
  auto stage_half = [&](int th, int tw, int half) {
    const int h0 = th * 8, w0 = tw * 32;
#pragma unroll
    for (int k = 0; k < 6; ++k) {
      const int u = k * 256 + tid;
      float* lb = &xt[(size_t)(half * HPAD + k * 256 + wv * 64) * 4];
      const int uc = u < HGRAN ? u : 0;
      const int pp = uc >> 2;
      const int c  = half * 4 + ((uc & 3) ^ ((pp >> 1) & 3));
      const int rr = pp / HCOLS, cc = pp - rr * HCOLS;
      const int hh = h0 - 1 + rr, wc = w0 - 1 + cc;
      const bool live = (u < HGRAN) & ((unsigned)hh < H_) & ((unsigned)wc < W_);
      const float* src = live
          ? img + ((size_t)(b * H_ + hh) * W_ + wc) * C_ + c * 4
          : zpool + lane * 4;
      dma16(src, lb);
    }
  };

  const int mr0 = wv * 2;  // this wave's 2 output rows (tile-relative)

  f32x16 acc0, acc1;
  float psum[4];
  auto reset_acc = [&]() {
#pragma unroll
    for (int i = 0; i < 16; ++i) { acc0[i] = 0.f; acc1[i] = 0.f; }
#pragma unroll
    for (int r = 0; r < 4; ++r) psum[r] = 0.f;
  };

  // ---- compute one channel-half from buffer `h` (r12's exact read path)
  auto compute_half = [&](int h) {
    const int hbase = h * (HPAD * 4);
#pragma unroll
    for (int dx = 0; dx < 3; ++dx) {
      bf16x8 af[4];
#pragma unroll
      for (int r = 0; r < 4; ++r) {
        const int p = (mr0 + r) * HCOLS + lp + dx;
        const int pj = (p >> 1) & 3;
        const int g0 = p * 4 + (hi2 ^ pj);
        const int g1 = p * 4 + ((hi2 + 1) ^ pj);
        const float4 f0 = *(const float4*)&xt[(size_t)(hbase + g0 * 4)];
        const float4 f1 = *(const float4*)&xt[(size_t)(hbase + g1 * 4)];
        psum[r] += f0.x * f0.x + f0.y * f0.y + f0.z * f0.z + f0.w * f0.w +
                   f1.x * f1.x + f1.y * f1.y + f1.z * f1.z + f1.w * f1.w;
        bf16x8 a;
        a[0] = (bf16_t)f0.x; a[1] = (bf16_t)f0.y;
        a[2] = (bf16_t)f0.z; a[3] = (bf16_t)f0.w;
        a[4] = (bf16_t)f1.x; a[5] = (bf16_t)f1.y;
        a[6] = (bf16_t)f1.z; a[7] = (bf16_t)f1.w;
        af[r] = a;
      }
#pragma unroll
      for (int dy = 0; dy < 3; ++dy) {
        const bf16x8 bf = bfrag[2 * (dy * 3 + dx) + h];
        acc0 = __builtin_amdgcn_mfma_f32_32x32x16_bf16(af[dy],     bf, acc0, 0, 0, 0);
        acc1 = __builtin_amdgcn_mfma_f32_32x32x16_bf16(af[dy + 1], bf, acc1, 0, 0, 0);
      }
    }
  };

  // ---- epilogue: EXACTLY 32 NT stores (counted by the vmcnt(32) below)
  auto epilogue = [&](int th, int tw) {
    const int h0 = th * 8, w0 = tw * 32;
#pragma unroll
    for (int r = 0; r < 4; ++r) psum[r] += __shfl_xor(psum[r], 32);
    float xinv[2];
    xinv[0] = 1.f / (sqrtf(fmaxf(psum[0] + psum[1] + psum[2], 1e-12f)) + qt);
    xinv[1] = 1.f / (sqrtf(fmaxf(psum[1] + psum[2] + psum[3], 1e-12f)) + qt);
#pragma unroll
    for (int t = 0; t < 2; ++t) {
      const f32x16& acc = t ? acc1 : acc0;
      const int obase = (b * H_ + h0 + mr0 + t) * W_ + w0;
      if (allfast) {
#pragma unroll
        for (int jj = 0; jj < 16; ++jj) {
          const int row = (jj & 3) + 8 * (jj >> 2) + 4 * (lane >> 5);
          const float xi = __shfl(xinv[t], row);
          const float sim = acc[jj] * xi * wnv;
          const float r = copysignf(fabsf(sim) + 1e-12f, sim);  // |x|^1
          __builtin_nontemporal_store(r, &out[(size_t)(obase + row) * F_ + lp]);
        }
      } else {
#pragma unroll
        for (int jj = 0; jj < 16; ++jj) {
          const int row = (jj & 3) + 8 * (jj >> 2) + 4 * (lane >> 5);
          const float xi = __shfl(xinv[t], row);
          const float sim = acc[jj] * xi * wnv;
          const float ps = fabsf(sim) + 1e-12f;
          float r = exp2f(efv * __log2f(ps));
          r = copysignf(r, sim);
          __builtin_nontemporal_store(r, &out[(size_t)(obase + row) * F_ + lp]);
        }
      }
    }
  };

  // ================= cross-tile pipelined schedule =================
  // --- tile 0 ---
  stage_half(th0, tw0, 0);                  // 6 DMA -> A
  stage_half(th0, tw0, 1);                  // 6 DMA -> B
  __builtin_amdgcn_sched_barrier(0);
  asm volatile("s_waitcnt vmcnt(6)" ::: "memory");  // bfrag + A done; B flies
  __builtin_amdgcn_sched_barrier(0);
  __builtin_amdgcn_s_barrier();
  __builtin_amdgcn_sched_barrier(0);

  reset_acc();
  compute_half(0);                          // reads A (B in flight)
  __syncthreads();                          // vmcnt(0)+barrier: B ready, A free

  stage_half(th1, tw1, 0);                  // 6 DMA -> A (t1 prefetch)
  __builtin_amdgcn_sched_barrier(0);        // pin DMA issue before stores
  compute_half(1);                          // reads B
  epilogue(th0, tw0);                       // 32 NT stores
  __builtin_amdgcn_sched_barrier(0);
  asm volatile("s_waitcnt vmcnt(32)" ::: "memory"); // 6 t1.h0 DMAs retired
  __builtin_amdgcn_sched_barrier(0);
  __builtin_amdgcn_s_barrier();             // all waves done reading B
  __builtin_amdgcn_sched_barrier(0);

  // --- tile 1 ---
  stage_half(th1, tw1, 1);                  // 6 DMA -> B
  __builtin_amdgcn_sched_barrier(0);
  reset_acc();
  compute_half(0);                          // reads A (B in flight)
  __syncthreads();                          // B ready
  compute_half(1);                          // reads B
  epilogue(th1, tw1);
}

// ---------------- launch ----------------------------------------------------
extern "C" void kernel_launch(void* const* d_in, const int* in_sizes, int n_in,
                              void* d_out, int out_size, void* d_ws, size_t ws_size,
                              hipStream_t stream) {
  const float* img = (const float*)d_in[0];
  const float* w   = (const float*)d_in[1];
  const float* p   = (const float*)d_in[2];
  const float* q   = (const float*)d_in[3];

  bf16_t* wfrag = (bf16_t*)d_ws;
  float*  winv  = (float*)((char*)d_ws + WFRAG_BYTES);
  float*  ef    = winv + 64;
  float*  zpool = ef + 64;   // 256 floats = 1KB zeros

  cos2d_prep<<<6, 256, 0, stream>>>(w, p, q, wfrag, winv, ef, zpool);
  // 784 blocks x 2 tiles each: image = bid&7 (== XCD), tiles bid>>3 and +98.
  cos2d_main<<<784, 256, 0, stream>>>(img, wfrag, winv, ef, q, zpool,
                                      (float*)d_out);
}

// Round 18
// 30.844 us; speedup vs baseline: 3.2115x; 2.5244x over previous
//
#include <hip/hip_runtime.h>
#include <hip/hip_bf16.h>

// CosSim2D (K=3, same-pad, C=32 -> F=32) on MI355X.
// Round 18: REVERT to round-12 (best measured: 31.4us).
//   r13-r17 post-mortems: every extension (more TLP, B-in-LDS, persistent
//   blocks, 2-tile counted-vmcnt pipeline) either spilled to scratch
//   (VGPR collapse + 100-200MB of scratch HBM traffic) or destroyed TLP.
//   r12 is the allocator's sweet spot: VGPR 156, zero scratch, 3 blk/CU,
//   split-half counted vmcnt hiding half the tile transfer.
//   Structure: fp32 halo tile DMA'd via global_load_lds in two chunk-halves
//   (vmcnt(6) after half0 -> compute h0 under half1's flight), bank-swizzled
//   LDS, fused bf16-cvt + x-norm-sumsq in the K-loop, 18 preloaded B-frags,
//   XCD-bijective tile map, NT stores, exp==1 guarded fast path.

#define H_ 224
#define W_ 224
#define C_ 32
#define F_ 32

#define NSTEP 18   // K = 288 = 18 * 16
#define HROWS 10   // staged halo rows (8 + 2)
#define HCOLS 34   // staged halo cols (32 + 2)
#define NPIX (HROWS * HCOLS)   // 340 pixels
#define HGRAN (NPIX * 4)       // 1360 16B granules per chunk-half
#define HPAD 1536              // 6 * 256: padded half (pad slots -> zpool)

typedef __bf16 bf16_t;
typedef bf16_t bf16x8 __attribute__((ext_vector_type(8)));
typedef float f32x16 __attribute__((ext_vector_type(16)));

#define WFRAG_BYTES (NSTEP * 64 * 8 * 2)  // 18432 B

__device__ __forceinline__ void dma16(const void* gp, void* lp) {
  __builtin_amdgcn_global_load_lds(
      (const __attribute__((address_space(1))) void*)gp,
      (__attribute__((address_space(3))) void*)lp, 16, 0, 0);
}

// ---------------- prep (6 blocks): w-norm, exponents, B-frags, zero pool ----
__global__ __launch_bounds__(256) void cos2d_prep(
    const float* __restrict__ w, const float* __restrict__ p,
    const float* __restrict__ q, bf16_t* __restrict__ wfrag,
    float* __restrict__ winv, float* __restrict__ ef,
    float* __restrict__ zpool) {
  const int tid = threadIdx.x;
  if (blockIdx.x == 0) {
    __shared__ float part[8][32];
    const int f = tid & 31, kg = tid >> 5;
    float s = 0.f;
#pragma unroll
    for (int i = 0; i < 36; ++i) {
      const float v = w[(kg + 8 * i) * F_ + f];
      s += v * v;
    }
    part[kg][f] = s;
    zpool[tid] = 0.f;     // 1KB zero pool for OOB/pad DMA sources
    __syncthreads();
    if (tid < 32) {
      float t = 0.f;
#pragma unroll
      for (int g = 0; g < 8; ++g) t += part[g][tid];
      const float qt = q[0] * q[0] * 0.1f;
      winv[tid] = 1.f / (sqrtf(fmaxf(t, 1e-12f)) + qt);
      ef[tid] = p[tid] * p[tid] * 0.01f;
    }
  } else {
    // B-fragment layout for mfma_f32_32x32x16_bf16:
    //   lane l holds col f = l&31, k = s2*16 + (l>>5)*8 + e  (e = 0..7).
    const int t = (blockIdx.x - 1) * 256 + tid;
    if (t < NSTEP * 64) {
      const int s2 = t >> 6, l = t & 63;
      const int ff = l & 31;
      union { bf16_t v[8]; uint4 u; } tv;
#pragma unroll
      for (int e = 0; e < 8; ++e) {
        const int kk = s2 * 16 + ((l >> 5) << 3) + e;
        tv.v[e] = (bf16_t)w[kk * F_ + ff];
      }
      *(uint4*)(wfrag + (size_t)t * 8) = tv.u;
    }
  }
}

// ---------------- main ------------------------------------------------------
__global__ __launch_bounds__(256, 3) void cos2d_main(
    const float* __restrict__ img, const bf16_t* __restrict__ wfrag,
    const float* __restrict__ winv, const float* __restrict__ ef,
    const float* __restrict__ q, const float* __restrict__ zpool,
    float* __restrict__ out) {
  // Two chunk-half regions of HPAD granules each. Within half h, pixel p's
  // chunk c (c>>2 == h) lives at granule h*HPAD + p*4 + ((c&3) ^ ((p>>1)&3))
  // -> 8 consecutive pixels at fixed c cover all 8 bank-groups.
  __shared__ __align__(16) float xt[2 * HPAD * 4];  // 49152 B -> 3 blk/CU

  const int tid = threadIdx.x;
  const int lane = tid & 63;
  const int wv = tid >> 6;
  const int lp = lane & 31;
  const int hi2 = (lane >> 5) * 2;   // chunk offset within half from lane-half

  // XCD-bijective mapping: image b == XCD (bid&7); tl walks rows per image.
  const int bid = blockIdx.x;
  const int b  = bid & 7;
  const int tl = bid >> 3;           // 0..195
  const int tw = tl % 7, th = tl / 7;
  const int h0 = th * 8, w0 = tw * 32;

  const float qt = q[0] * q[0] * 0.1f;
  const float efv = ef[lp];
  const float wnv = winv[lp];
  const bool allfast = __all(__builtin_fabsf(efv - 1.0f) < 1e-6f);

  // ---- preload all 18 B-fragments (overlap the DMA batch)
  bf16x8 bfrag[NSTEP];
  const bf16x8* wf4 = (const bf16x8*)wfrag;
#pragma unroll
  for (int s2 = 0; s2 < NSTEP; ++s2) bfrag[s2] = wf4[s2 * 64 + lane];

  // ---- DMA staging: iters 0-5 = chunk-half 0, iters 6-11 = chunk-half 1.
  // Exactly 12 DMA per thread (pad/OOB slots pull zeros from zpool).
#pragma unroll
  for (int k = 0; k < 12; ++k) {
    const int s = k * 256 + tid;
    const int half = k >= 6;
    const int u = s - half * HPAD;         // granule within half
    float* lb = &xt[(size_t)(k * 256 + wv * 64) * 4];  // wave-uniform base
    const int uc = u < HGRAN ? u : 0;
    const int pp = uc >> 2;
    const int c  = half * 4 + ((uc & 3) ^ ((pp >> 1) & 3));
    const int rr = pp / HCOLS, cc = pp - rr * HCOLS;
    const int hh = h0 - 1 + rr, wc = w0 - 1 + cc;
    const bool live = (u < HGRAN) & ((unsigned)hh < H_) & ((unsigned)wc < W_);
    const float* src = live
        ? img + ((size_t)(b * H_ + hh) * W_ + wc) * C_ + c * 4
        : zpool + lane * 4;
    dma16(src, lb);
  }

  const int mr0 = wv * 2;  // this wave's 2 output rows (tile-relative)

  f32x16 acc0, acc1;
#pragma unroll
  for (int i = 0; i < 16; ++i) { acc0[i] = 0.f; acc1[i] = 0.f; }
  float psum[4] = {0.f, 0.f, 0.f, 0.f};

  // ---- split-wait pipeline over chunk halves
#pragma unroll
  for (int h = 0; h < 2; ++h) {
    if (h == 0) {
      // drain bfrag + half0 (all issued before half1); keep half1 in flight
      asm volatile("s_waitcnt vmcnt(6)" ::: "memory");
    } else {
      asm volatile("s_waitcnt vmcnt(0)" ::: "memory");
    }
    __builtin_amdgcn_sched_barrier(0);
    __builtin_amdgcn_s_barrier();      // all waves' half-h DMAs retired
    __builtin_amdgcn_sched_barrier(0);

    const int hbase = h * (HPAD * 4);  // float offset of half region
#pragma unroll
    for (int dx = 0; dx < 3; ++dx) {
      bf16x8 af[4];
#pragma unroll
      for (int r = 0; r < 4; ++r) {
        const int p = (mr0 + r) * HCOLS + lp + dx;
        const int pj = (p >> 1) & 3;
        const int g0 = p * 4 + (hi2 ^ pj);
        const int g1 = p * 4 + ((hi2 + 1) ^ pj);
        const float4 f0 = *(const float4*)&xt[(size_t)(hbase + g0 * 4)];
        const float4 f1 = *(const float4*)&xt[(size_t)(hbase + g1 * 4)];
        psum[r] += f0.x * f0.x + f0.y * f0.y + f0.z * f0.z + f0.w * f0.w +
                   f1.x * f1.x + f1.y * f1.y + f1.z * f1.z + f1.w * f1.w;
        bf16x8 a;
        a[0] = (bf16_t)f0.x; a[1] = (bf16_t)f0.y;
        a[2] = (bf16_t)f0.z; a[3] = (bf16_t)f0.w;
        a[4] = (bf16_t)f1.x; a[5] = (bf16_t)f1.y;
        a[6] = (bf16_t)f1.z; a[7] = (bf16_t)f1.w;
        af[r] = a;
      }
#pragma unroll
      for (int dy = 0; dy < 3; ++dy) {
        const bf16x8 bf = bfrag[2 * (dy * 3 + dx) + h];
        acc0 = __builtin_amdgcn_mfma_f32_32x32x16_bf16(af[dy],     bf, acc0, 0, 0, 0);
        acc1 = __builtin_amdgcn_mfma_f32_32x32x16_bf16(af[dy + 1], bf, acc1, 0, 0, 0);
      }
    }
  }

  // x-norm from fused sums: lane and lane^32 hold complementary 16 channels.
#pragma unroll
  for (int r = 0; r < 4; ++r) psum[r] += __shfl_xor(psum[r], 32);
  float xinv[2];
  xinv[0] = 1.f / (sqrtf(fmaxf(psum[0] + psum[1] + psum[2], 1e-12f)) + qt);
  xinv[1] = 1.f / (sqrtf(fmaxf(psum[1] + psum[2] + psum[3], 1e-12f)) + qt);

  // epilogue: C/D col = lane&31 (filter), row = (j&3)+8*(j>>2)+4*(lane>>5).
#pragma unroll
  for (int t = 0; t < 2; ++t) {
    const f32x16& acc = t ? acc1 : acc0;
    const int obase = (b * H_ + h0 + mr0 + t) * W_ + w0;
    if (allfast) {
#pragma unroll
      for (int jj = 0; jj < 16; ++jj) {
        const int row = (jj & 3) + 8 * (jj >> 2) + 4 * (lane >> 5);
        const float xi = __shfl(xinv[t], row);
        const float sim = acc[jj] * xi * wnv;
        const float r = copysignf(fabsf(sim) + 1e-12f, sim);  // |x|^1 path
        __builtin_nontemporal_store(r, &out[(size_t)(obase + row) * F_ + lp]);
      }
    } else {
#pragma unroll
      for (int jj = 0; jj < 16; ++jj) {
        const int row = (jj & 3) + 8 * (jj >> 2) + 4 * (lane >> 5);
        const float xi = __shfl(xinv[t], row);
        const float sim = acc[jj] * xi * wnv;
        const float ps = fabsf(sim) + 1e-12f;
        float r = exp2f(efv * __log2f(ps));
        r = copysignf(r, sim);
        __builtin_nontemporal_store(r, &out[(size_t)(obase + row) * F_ + lp]);
      }
    }
  }
}

// ---------------- launch ----------------------------------------------------
extern "C" void kernel_launch(void* const* d_in, const int* in_sizes, int n_in,
                              void* d_out, int out_size, void* d_ws, size_t ws_size,
                              hipStream_t stream) {
  const float* img = (const float*)d_in[0];
  const float* w   = (const float*)d_in[1];
  const float* p   = (const float*)d_in[2];
  const float* q   = (const float*)d_in[3];

  bf16_t* wfrag = (bf16_t*)d_ws;
  float*  winv  = (float*)((char*)d_ws + WFRAG_BYTES);
  float*  ef    = winv + 64;
  float*  zpool = ef + 64;   // 256 floats = 1KB zeros

  cos2d_prep<<<6, 256, 0, stream>>>(w, p, q, wfrag, winv, ef, zpool);
  // 1568 blocks: image = bid&7 (== XCD), tile-in-image = bid>>3.
  cos2d_main<<<1568, 256, 0, stream>>>(img, wfrag, winv, ef, q, zpool,
                                       (float*)d_out);
}